// Round 15
// baseline (5831.119 us; speedup 1.0000x reference)
//
#include <hip/hip_runtime.h>

#define MDIM 512
#define NDIM 8192
#define KDIM 8192

typedef float v4f __attribute__((ext_vector_type(4)));
typedef int   v4i __attribute__((ext_vector_type(4)));
typedef char  c16 __attribute__((ext_vector_type(16)));

#define GLDS16(g, l)                                                    \
  __builtin_amdgcn_global_load_lds(                                     \
      (const __attribute__((address_space(1))) void*)(g),               \
      (__attribute__((address_space(3))) void*)(l), 16, 0, 0)
#define SB __builtin_amdgcn_sched_barrier(0)

// r8/r14 swizzle: byte offset in a 64-row x 64k int8 tile (4KB), 0 conflicts.
__device__ __forceinline__ int swb(int row, int g) {
  return ((row >> 1) << 7) + (((((row & 1) << 2) | g) ^ ((row >> 1) & 7)) << 4);
}

// Fused producer-consumer kernel. MODE 0: overlapped pipeline (all 512
// blocks co-resident; flags gate chunk availability). MODE 1: produce only.
// MODE 2: gemm only (no spins). Gemm core is r14's exactly (BM=64, BN=128,
// BK=128, 8 waves, 48KB dbuf, counted vmcnt(3), scale-fold per phase).
template <int MODE>
__global__ __launch_bounds__(512, 4) void mega_kernel(
    const int* __restrict__ wq, const float* __restrict__ x,
    const float* __restrict__ wsc, char* __restrict__ w8,
    char* __restrict__ xq, float* __restrict__ ax, int* __restrict__ cflag,
    int* __restrict__ xflag, float* __restrict__ out) {
  __shared__ char lA[2][8192];
  __shared__ char lB[2][16384];
  __shared__ float smx[8];

  const int b = blockIdx.x;
  const int c = b & 7;
  const int s = b >> 3;
  const int mt = s & 7;
  const int u = s >> 3;
  const int nt2 = c * 8 + u;  // panel id; all 8 consumers share nt2
  const int t = threadIdx.x;
  const int w = t >> 6, l = t & 63;

  // --- produce: one k128-chunk (16KB int8) of panel nt2; wave-parallel ---
  auto compress_chunk = [&](int g) {
    const int row = w * 16 + (l & 15);   // panel row 0..127
    const int koff = (l >> 4) * 32;      // 32 ints per lane
    const int* src = wq + ((size_t)(nt2 * 128 + row) << 13) + g * 128 + koff;
    v4i a[8];
#pragma unroll
    for (int h = 0; h < 8; ++h) a[h] = *(const v4i*)(src + h * 4);
#pragma unroll
    for (int hu = 0; hu < 2; ++hu) {
      c16 q;
#pragma unroll
      for (int e = 0; e < 16; ++e) q[e] = (char)a[hu * 4 + (e >> 2)][e & 3];
      const int kk = koff + hu * 16;
      const int kt = g * 2 + (kk >> 6);
      const int g16 = (kk & 63) >> 4;
      *(c16*)(w8 + ((size_t)((nt2 * 2 + (row >> 6)) * 128 + kt) << 12) +
              swb(row & 63, g16)) = q;
    }
    asm volatile("s_waitcnt vmcnt(0)" ::: "memory");  // wave's stores done
    __threadfence();                                  // visible device-wide
    if (l == 0) atomicAdd(&cflag[nt2 * 64 + g], 1);   // 8 waves -> ==8 done
  };

  // --- produce: quantize one x row (per-row scale), flag per mt-group ---
  auto quant_row = [&]() {
    const int row = mt * 64 + c * 8 + u;  // bijective over 512
    const float* xr = x + ((size_t)row << 13) + t * 16;
    v4f v[4];
#pragma unroll
    for (int i = 0; i < 4; ++i) v[i] = *(const v4f*)(xr + i * 4);
    float mx = 0.f;
#pragma unroll
    for (int i = 0; i < 4; ++i)
#pragma unroll
      for (int r = 0; r < 4; ++r) mx = fmaxf(mx, fabsf(v[i][r]));
#pragma unroll
    for (int d = 1; d < 64; d <<= 1) mx = fmaxf(mx, __shfl_xor(mx, d));
    if (l == 0) smx[w] = mx;
    __syncthreads();
    mx = smx[0];
#pragma unroll
    for (int i = 1; i < 8; ++i) mx = fmaxf(mx, smx[i]);
    const float inv = (mx > 0.f) ? 127.f / mx : 0.f;
    if (t == 0) ax[row] = mx / 127.f;
    c16 q;
#pragma unroll
    for (int e = 0; e < 16; ++e) {
      float f = fminf(fmaxf(v[e >> 2][e & 3] * inv, -127.f), 127.f);
      q[e] = (char)__float2int_rn(f);
    }
    const int kt = t >> 2, g16 = t & 3;
    *(c16*)(xq + ((size_t)(mt * 128 + kt) << 12) + swb(row & 63, g16)) = q;
    asm volatile("s_waitcnt vmcnt(0)" ::: "memory");
    __threadfence();
    __syncthreads();
    if (t == 0) atomicAdd(&xflag[mt], 1);  // ==64 -> xq[mt] complete
  };

  auto spin_chunk = [&](int g) {
    while (__hip_atomic_load(&cflag[nt2 * 64 + g], __ATOMIC_ACQUIRE,
                             __HIP_MEMORY_SCOPE_AGENT) < 8)
      __builtin_amdgcn_s_sleep(4);
  };
  auto spin_x = [&]() {
    while (__hip_atomic_load(&xflag[mt], __ATOMIC_ACQUIRE,
                             __HIP_MEMORY_SCOPE_AGENT) < 64)
      __builtin_amdgcn_s_sleep(4);
  };

  // --- gemm (r14 exact) ---
  const int wm = (w >> 2) * 32;
  const int wn = (w & 3) * 32;
  const int l15 = l & 15, qq = l >> 4;
  v4i acc[2][2] = {};
  v4f facc[2][2] = {};

  auto issue = [&](int tt) {
    const int buf = tt & 1;
#pragma unroll
    for (int it = 0; it < 3; ++it) {
      const int uu = w * 3 + it;
      const int reg = uu >> 2, qt = uu & 3;
      const char* src;
      if (reg < 2) {
        src = xq + ((size_t)(mt * 128 + tt * 2 + reg) << 12);
      } else {
        const int nh = (reg - 2) >> 1, kh = (reg - 2) & 1;
        src = w8 + ((size_t)((nt2 * 2 + nh) * 128 + tt * 2 + kh) << 12);
      }
      src += qt * 1024 + (size_t)l * 16;
      if (reg < 2)
        GLDS16(src, &lA[buf][reg * 4096 + qt * 1024]);
      else
        GLDS16(src, &lB[buf][(reg - 2) * 4096 + qt * 1024]);
    }
  };

  if (MODE == 1) {  // produce-only fallback
    quant_row();
#pragma unroll 1
    for (int g = 8 * mt; g < 8 * mt + 8; ++g) compress_chunk(g);
    return;
  }

  if (MODE == 0) {
    quant_row();
    if (mt == 0) {  // front-load the first 4 chunks of this panel
#pragma unroll 1
      for (int g = 0; g < 4; ++g) compress_chunk(g);
    }
    spin_x();
    spin_chunk(0);
  }

  issue(0);
#pragma unroll 1
  for (int p = 0; p < 64; ++p) {
    const int cur = p & 1;
    SB;
    __builtin_amdgcn_s_barrier();  // all waves done reading buf[cur^1]
    SB;
    if (MODE == 0) {
      const int gc = p + 4;  // produce chunk g at phase g-4 (3-phase cushion)
      if (gc < 64 && (gc >> 3) == mt) compress_chunk(gc);
    }
    if (p + 1 < 64) {
      if (MODE == 0) spin_chunk(p + 1);  // in-order retire drains tile p too
      issue(p + 1);
      SB;
      asm volatile("s_waitcnt vmcnt(3)" ::: "memory");  // tile p confirmed
    } else {
      asm volatile("s_waitcnt vmcnt(0)" ::: "memory");
    }
    SB;
    __builtin_amdgcn_s_barrier();  // buf[cur] visible to all waves
    SB;

#pragma unroll
    for (int kk = 0; kk < 2; ++kk) {
      v4i af[2], bq[2];
#pragma unroll
      for (int i = 0; i < 2; ++i)
        af[i] = *(const v4i*)&lA[cur][kk * 4096 + swb(wm + i * 16 + l15, qq)];
#pragma unroll
      for (int j = 0; j < 2; ++j) {
        const int rb = wn + j * 16 + l15;
        bq[j] = *(const v4i*)&lB[cur][(rb >> 6) * 8192 + kk * 4096 +
                                      swb(rb & 63, qq)];
      }
#pragma unroll
      for (int i = 0; i < 2; ++i)
#pragma unroll
        for (int j = 0; j < 2; ++j)
          acc[i][j] = __builtin_amdgcn_mfma_i32_16x16x64_i8(
              af[i], bq[j], acc[i][j], 0, 0, 0);
    }

    const float sc = wsc[nt2 * 64 + p];  // one (n128,k128) scale block
#pragma unroll
    for (int i = 0; i < 2; ++i)
#pragma unroll
      for (int j = 0; j < 2; ++j) {
#pragma unroll
        for (int r = 0; r < 4; ++r)
          facc[i][j][r] = fmaf(sc, (float)acc[i][j][r], facc[i][j][r]);
        acc[i][j] = v4i{0, 0, 0, 0};
      }
  }

#pragma unroll
  for (int i = 0; i < 2; ++i) {
    const int mrow = mt * 64 + wm + i * 16 + qq * 4;
#pragma unroll
    for (int j = 0; j < 2; ++j) {
      const int ocol = nt2 * 128 + wn + j * 16 + l15;
#pragma unroll
      for (int r = 0; r < 4; ++r)
        out[(size_t)(mrow + r) * NDIM + ocol] = ax[mrow + r] * facc[i][j][r];
    }
  }
}

extern "C" void kernel_launch(void* const* d_in, const int* in_sizes, int n_in,
                              void* d_out, int out_size, void* d_ws,
                              size_t ws_size, hipStream_t stream) {
  const float* x = (const float*)d_in[0];
  const int* wq = (const int*)d_in[1];
  const float* wsc = (const float*)d_in[2];
  float* out = (float*)d_out;

  const size_t W8 = (size_t)NDIM * KDIM;  // 64 MB
  const size_t XQ = (size_t)MDIM * KDIM;  // 4 MB
  const size_t AXPAD = 4096;              // 512 floats, padded
  const size_t CF = 4096 * sizeof(int);   // 64 panels x 64 chunks
  const size_t XF = 64;

  char* w8 = (char*)d_ws;
  char* xq = (char*)d_ws + W8;
  float* ax = (float*)((char*)d_ws + W8 + XQ);
  int* cflag = (int*)((char*)d_ws + W8 + XQ + AXPAD);
  int* xflag = cflag + 4096;

  if (ws_size >= W8 + XQ + AXPAD + CF + XF) {
    hipMemsetAsync(cflag, 0, CF + XF, stream);  // flags fresh each launch
    mega_kernel<0><<<dim3(512), dim3(512), 0, stream>>>(
        wq, x, wsc, w8, xq, ax, cflag, xflag, out);
  } else {
    mega_kernel<1><<<dim3(512), dim3(512), 0, stream>>>(
        wq, x, wsc, w8, xq, ax, cflag, xflag, out);
    mega_kernel<2><<<dim3(512), dim3(512), 0, stream>>>(
        wq, x, wsc, w8, xq, ax, cflag, xflag, out);
  }
}

// Round 16
// 127.550 us; speedup vs baseline: 45.7162x; 45.7162x over previous
//
#include <hip/hip_runtime.h>

#define MDIM 512
#define NDIM 8192
#define KDIM 8192

typedef float v4f __attribute__((ext_vector_type(4)));
typedef int   v4i __attribute__((ext_vector_type(4)));
typedef char  c16 __attribute__((ext_vector_type(16)));

#define GLDS16(g, l)                                                    \
  __builtin_amdgcn_global_load_lds(                                     \
      (const __attribute__((address_space(1))) void*)(g),               \
      (__attribute__((address_space(3))) void*)(l), 16, 0, 0)
#define SB __builtin_amdgcn_sched_barrier(0)

// r8 swizzle: byte offset in a 64-row x 64k int8 tile (4KB), 0 conflicts.
// Producers write it; glds copies linearly; gemm ds_read applies it.
__device__ __forceinline__ int swb(int row, int g) {
  return ((row >> 1) << 7) + (((((row & 1) << 2) | g) ^ ((row >> 1) & 7)) << 4);
}

// Merged producer (r14 exact):
//  blocks [0,16384): wq int32 -> int8, w8 tiles [ntile64(128)][kt64(128)][4KB].
//  blocks [16384,16896): x fp32 -> int8 + per-row scale ax,
//                        xq tiles [mtile64(8)][kt64(128)][4KB].
__global__ __launch_bounds__(256) void produce_kernel(
    const int* __restrict__ wq, const float* __restrict__ x,
    char* __restrict__ w8, char* __restrict__ xq, float* __restrict__ ax) {
  if (blockIdx.x < 16384) {
    const int tid = blockIdx.x * 256 + threadIdx.x;
    const int R = tid >> 9;     // weight row 0..8191
    const int k16 = tid & 511;  // 16-int group
    const int* src = wq + ((size_t)R << 13) + k16 * 16;
    v4i a[4];
#pragma unroll
    for (int h = 0; h < 4; ++h) a[h] = *(const v4i*)(src + h * 4);
    c16 q;
#pragma unroll
    for (int h = 0; h < 4; ++h) {
      q[h * 4 + 0] = (char)a[h][0];
      q[h * 4 + 1] = (char)a[h][1];
      q[h * 4 + 2] = (char)a[h][2];
      q[h * 4 + 3] = (char)a[h][3];
    }
    const int ntile = R >> 6, r = R & 63;
    const int kt = k16 >> 2, g = k16 & 3;
    *(c16*)(w8 + ((size_t)(ntile * 128 + kt) << 12) + swb(r, g)) = q;
  } else {
    const int m = blockIdx.x - 16384;
    const int t = threadIdx.x;
    const float* row = x + ((size_t)m << 13);
    v4f v[8];
    float mx = 0.f;
#pragma unroll
    for (int i = 0; i < 8; ++i) {
      v[i] = *(const v4f*)(row + t * 32 + i * 4);
#pragma unroll
      for (int r = 0; r < 4; ++r) mx = fmaxf(mx, fabsf(v[i][r]));
    }
#pragma unroll
    for (int d = 1; d < 64; d <<= 1) mx = fmaxf(mx, __shfl_xor(mx, d));
    __shared__ float smx[4];
    if ((t & 63) == 0) smx[t >> 6] = mx;
    __syncthreads();
    mx = fmaxf(fmaxf(smx[0], smx[1]), fmaxf(smx[2], smx[3]));
    const float inv = (mx > 0.f) ? 127.f / mx : 0.f;
    if (t == 0) ax[m] = mx / 127.f;
    const int mt = m >> 6, r = m & 63;  // 64-row xq tiles
#pragma unroll
    for (int g2 = 0; g2 < 2; ++g2) {
      c16 q;
#pragma unroll
      for (int e = 0; e < 16; ++e) {
        const int idx = g2 * 4 + (e >> 2);
        float f = fminf(fmaxf(v[idx][e & 3] * inv, -127.f), 127.f);
        q[e] = (char)__float2int_rn(f);
      }
      const int k16 = t * 2 + g2;
      const int kt = k16 >> 2, g = k16 & 3;
      *(c16*)(xq + ((size_t)(mt * 128 + kt) << 12) + swb(r, g)) = q;
    }
  }
}

template <int KS>
__global__ __launch_bounds__(256) void reduce_kernel(const float* __restrict__ p,
                                                     float* __restrict__ out) {
  const size_t i = ((size_t)blockIdx.x * 256 + threadIdx.x) * 4;
  v4f a = *(const v4f*)(p + i);
#pragma unroll
  for (int s = 1; s < KS; ++s) a += *(const v4f*)(p + (size_t)s * MDIM * NDIM + i);
  *(v4f*)(out + i) = a;
}

// Pure-i8 GEMM, LDS-read-BW lever: 64x64 WAVE TILES (2 ds_read_b128 per
// 4 MFMA -> ratio 0.5, half of r14's 1.0). Block 128x128, 4 waves (2x2),
// BK=128, LDS 64KB dbuf -> 2 blocks/CU. r14 sync structure: 2 barriers,
// counted vmcnt(8) (8 glds/wave/phase), scale-fold per phase (k128 block).
template <int KS>
__global__ __launch_bounds__(256, 2) void gemm_i8_kernel(
    const char* __restrict__ xq, const char* __restrict__ w8,
    const float* __restrict__ wsc, const float* __restrict__ ax,
    float* __restrict__ outp) {
  constexpr int NPH = 64 / KS;   // k128 phases per block
  __shared__ char lA[2][16384];  // 128 rows x 128k int8
  __shared__ char lB[2][16384];

  // XCD swizzle: XCD c owns nt2 in [c*8, c*8+8) x all mt,kh.
  const int b = blockIdx.x;
  const int c = b & 7;
  const int s = b >> 3;
  const int mt = s & 3;                                   // m-tile of 128
  const int kh = (KS > 1) ? ((s >> 2) & (KS - 1)) : 0;
  const int nt2 = c * 8 + ((KS > 1) ? (s >> 3) : (s >> 2));
  const int ktg0 = kh * (128 / KS);  // global k64-tile base

  const int t = threadIdx.x;
  const int w = t >> 6, l = t & 63;
  const int wm = (w >> 1) * 64;  // wave tile 64x64
  const int wn = (w & 1) * 64;
  const int l15 = l & 15, q = l >> 4;

  v4i acc[4][4] = {};
  v4f facc[4][4] = {};

  // staging: 32 x 1KB units/phase (A: 2 rowhalf x 2 kt x 4 qt; B same);
  // wave w covers units w*8..w*8+7. Linear LDS dest; sources are the
  // producers' swizzled 4KB tiles (rule 21 pair).
  auto issue = [&](int tt) {
    const int buf = tt & 1;
#pragma unroll
    for (int it = 0; it < 8; ++it) {
      const int uu = w * 8 + it;
      const int side = uu >> 4;       // 0=A, 1=B
      const int h = (uu >> 3) & 1;    // 64-row half
      const int kt = (uu >> 2) & 1;   // k64 within phase
      const int qt = uu & 3;          // 16-row quarter
      const int ktile = ktg0 + tt * 2 + kt;
      const char* src =
          (side == 0)
              ? xq + ((size_t)((mt * 2 + h) * 128 + ktile) << 12)
              : w8 + ((size_t)((nt2 * 2 + h) * 128 + ktile) << 12);
      src += qt * 1024 + (size_t)l * 16;
      char* dst = (side == 0) ? &lA[buf][h * 8192 + kt * 4096 + qt * 1024]
                              : &lB[buf][h * 8192 + kt * 4096 + qt * 1024];
      GLDS16(src, dst);
    }
  };

  issue(0);
#pragma unroll 1
  for (int tt = 0; tt < NPH; ++tt) {
    const int cur = tt & 1;
    SB;
    __builtin_amdgcn_s_barrier();  // all waves done reading buf[cur^1]
    SB;
    if (tt + 1 < NPH) issue(tt + 1);  // -> buf[cur^1], stays in flight
    SB;
    if (tt + 1 < NPH)
      asm volatile("s_waitcnt vmcnt(8)" ::: "memory");  // phase tt landed
    else
      asm volatile("s_waitcnt vmcnt(0)" ::: "memory");
    SB;
    __builtin_amdgcn_s_barrier();  // buf[cur] visible to all waves
    SB;

#pragma unroll
    for (int kk = 0; kk < 2; ++kk) {  // two k64 sub-tiles of the phase
      v4i af[4], bq[4];
#pragma unroll
      for (int i = 0; i < 4; ++i) {
        const int ra = wm + i * 16 + l15;
        af[i] = *(const v4i*)&lA[cur][(ra >> 6) * 8192 + kk * 4096 +
                                      swb(ra & 63, q)];
      }
#pragma unroll
      for (int j = 0; j < 4; ++j) {
        const int rb = wn + j * 16 + l15;
        bq[j] = *(const v4i*)&lB[cur][(rb >> 6) * 8192 + kk * 4096 +
                                      swb(rb & 63, q)];
      }
#pragma unroll
      for (int i = 0; i < 4; ++i)
#pragma unroll
        for (int j = 0; j < 4; ++j)
          acc[i][j] = __builtin_amdgcn_mfma_i32_16x16x64_i8(
              af[i], bq[j], acc[i][j], 0, 0, 0);
    }

    const float sc = wsc[nt2 * 64 + (ktg0 >> 1) + tt];  // (n128,k128) block
#pragma unroll
    for (int i = 0; i < 4; ++i)
#pragma unroll
      for (int j = 0; j < 4; ++j) {
#pragma unroll
        for (int r = 0; r < 4; ++r)
          facc[i][j][r] = fmaf(sc, (float)acc[i][j][r], facc[i][j][r]);
        acc[i][j] = v4i{0, 0, 0, 0};
      }
  }

  float* dst = outp + ((KS > 1) ? (size_t)kh * MDIM * NDIM : 0);
#pragma unroll
  for (int i = 0; i < 4; ++i) {
    const int mrow = mt * 128 + wm + i * 16 + q * 4;
#pragma unroll
    for (int j = 0; j < 4; ++j) {
      const int ocol = nt2 * 128 + wn + j * 16 + l15;
#pragma unroll
      for (int r = 0; r < 4; ++r)
        dst[(size_t)(mrow + r) * NDIM + ocol] = ax[mrow + r] * facc[i][j][r];
    }
  }
}

extern "C" void kernel_launch(void* const* d_in, const int* in_sizes, int n_in,
                              void* d_out, int out_size, void* d_ws,
                              size_t ws_size, hipStream_t stream) {
  const float* x = (const float*)d_in[0];
  const int* wq = (const int*)d_in[1];
  const float* wsc = (const float*)d_in[2];
  float* out = (float*)d_out;

  const size_t W8 = (size_t)NDIM * KDIM;      // 64 MB
  const size_t XQ = (size_t)MDIM * KDIM;      // 4 MB
  const size_t AX = 65536;                    // padded
  const size_t PS = (size_t)MDIM * NDIM * 4;  // 16 MB per partial

  char* w8 = (char*)d_ws;
  char* xq = (char*)d_ws + W8;
  float* ax = (float*)((char*)d_ws + W8 + XQ);
  float* part = (float*)((char*)d_ws + W8 + XQ + AX);

  produce_kernel<<<dim3(16384 + MDIM), dim3(256), 0, stream>>>(wq, x, w8, xq, ax);

  if (ws_size >= W8 + XQ + AX + 2 * PS) {
    gemm_i8_kernel<2><<<dim3(512), dim3(256), 0, stream>>>(xq, w8, wsc, ax, part);
    reduce_kernel<2><<<dim3((MDIM * NDIM) / (256 * 4)), dim3(256), 0, stream>>>(part, out);
  } else {
    gemm_i8_kernel<1><<<dim3(256), dim3(256), 0, stream>>>(xq, w8, wsc, ax, out);
  }
}